// Round 4
// baseline (410.352 us; speedup 1.0000x reference)
//
#include <hip/hip_runtime.h>
#include <hip/hip_bf16.h>

#define NN 100000
#define NE 1600000
#define NCHUNK ((NN + 127) / 128)   // 782 (gemm row chunks of 128)
#define NPB 512                      // nodes per bucket (pow2, shift 9)
#define NB 256                       // bucket slots (196 active)
#define CHUNK 8192                   // edges per bscatter block
#define NCH ((NE + CHUNK - 1) / CHUNK)  // 196

typedef __attribute__((ext_vector_type(8))) short short8;
typedef __attribute__((ext_vector_type(4))) float float4v;

__device__ __forceinline__ unsigned short f2bf(float f) {
    unsigned int b = __float_as_uint(f);
    return (unsigned short)((b + 0x7fffu + ((b >> 16) & 1u)) >> 16);
}
__device__ __forceinline__ unsigned int pack_bf16(float lo, float hi) {
    return (unsigned int)f2bf(lo) | ((unsigned int)f2bf(hi) << 16);
}
__device__ __forceinline__ float bflo(unsigned int u) { return __uint_as_float(u << 16); }
__device__ __forceinline__ float bfhi(unsigned int u) { return __uint_as_float(u & 0xffff0000u); }

__device__ __forceinline__ void addp(float* a, uint4 u) {
    a[0] += bflo(u.x); a[1] += bfhi(u.x);
    a[2] += bflo(u.y); a[3] += bfhi(u.y);
    a[4] += bflo(u.z); a[5] += bfhi(u.z);
    a[6] += bflo(u.w); a[7] += bfhi(u.w);
}

// ---- fused prep: xconv (blocks 0..24999), wconv (25000..25127), bcount (25128..25383) ----
__global__ void k_prep(const float* x, const float* W1l, const float* W1r,
                       const float* W2l, const float* W2r, const int* ei,
                       unsigned int* axb_u, unsigned short* wb1, unsigned short* wb2,
                       int* bcnt) {
    __shared__ int hh[NB];
    int b = blockIdx.x, t = threadIdx.x;
    if (b < 25000) {
        int tt = b * 256 + t;
        int node = tt >> 6, i = tt & 63;
        float2 v = ((const float2*)x)[tt];
        axb_u[(size_t)node * 128 + 64 + i] = pack_bf16(v.x, v.y);
    } else if (b < 25128) {
        int i = (b - 25000) * 256 + t;        // < 32768
        int r1 = i >> 7, c1 = i & 127;        // W1l/W1r are 256x128
        wb1[r1 * 256 + c1]       = f2bf(W1l[i]);
        wb1[r1 * 256 + 128 + c1] = f2bf(W1r[i]);
        wb2[i]         = f2bf(W2l[i]);        // 128x256, k contiguous
        wb2[32768 + i] = f2bf(W2r[i]);
    } else {
        hh[t] = 0;
        __syncthreads();
        int e0 = (b - 25128) * 6250;          // 256 * 6250 = NE exactly
        for (int e = e0 + t; e < e0 + 6250; e += 256)
            atomicAdd(&hh[ei[NE + e] >> 9], 1);
        __syncthreads();
        if (hh[t]) atomicAdd(&bcnt[t], hh[t]);
    }
}

__global__ void k_bscan(const int* bcnt, int* boff, int* bcur) {
    __shared__ int s[NB];
    int t = threadIdx.x;
    int v = bcnt[t];
    s[t] = v;
    __syncthreads();
    for (int d = 1; d < NB; d <<= 1) {
        int val = (t >= d) ? s[t - d] : 0;
        __syncthreads();
        s[t] += val;
        __syncthreads();
    }
    boff[t + 1] = s[t];
    if (t == 0) boff[0] = 0;
    bcur[t] = s[t] - v;   // exclusive
}

__global__ __launch_bounds__(256) void k_bscatter(const int* ei, int* bcur, uint2* pairs) {
    __shared__ uint2 buf[CHUNK];       // 64 KB
    __shared__ int cnt[NB];
    __shared__ int lbase[NB];
    __shared__ int lcur[NB];
    __shared__ int gpos[NB];
    int t = threadIdx.x;
    int e0 = blockIdx.x * CHUNK;
    int nedge = NE - e0; if (nedge > CHUNK) nedge = CHUNK;
    cnt[t] = 0;
    __syncthreads();
    for (int i = t; i < nedge; i += 256)
        atomicAdd(&cnt[ei[NE + e0 + i] >> 9], 1);
    __syncthreads();
    int v = cnt[t];
    lcur[t] = v;
    __syncthreads();
    for (int d = 1; d < NB; d <<= 1) {
        int val = (t >= d) ? lcur[t - d] : 0;
        __syncthreads();
        lcur[t] += val;
        __syncthreads();
    }
    lbase[t] = lcur[t] - v;
    gpos[t] = atomicAdd(&bcur[t], v);
    __syncthreads();
    lcur[t] = lbase[t];
    __syncthreads();
    for (int i = t; i < nedge; i += 256) {
        int r = ei[e0 + i], c = ei[NE + e0 + i];
        int b = c >> 9;
        int p = atomicAdd(&lcur[b], 1);
        buf[p] = make_uint2((unsigned)r, (unsigned)c);
    }
    __syncthreads();
    int n = cnt[t], lb = lbase[t], gp = gpos[t];
    for (int i = 0; i < n; i++)
        pairs[gp + i] = buf[lb + i];
}

__global__ __launch_bounds__(256) void k_build(const uint2* pairs, const int* boff,
                                               int* off, int* deg, int* csr) {
    __shared__ int ldeg[NPB];
    __shared__ int lcur[NPB];
    __shared__ int sscan[256];
    int b = blockIdx.x;
    int nbase = b * NPB;
    if (nbase >= NN) return;
    int t = threadIdx.x;
    int base = boff[b], cntb = boff[b + 1] - base;
    ldeg[t] = 0; ldeg[t + 256] = 0;
    __syncthreads();
    for (int i = t; i < cntb; i += 256) {
        uint2 pr = pairs[base + i];
        atomicAdd(&ldeg[pr.y - nbase], 1);
    }
    __syncthreads();
    int d0 = ldeg[2 * t], d1 = ldeg[2 * t + 1];
    int v = d0 + d1;
    sscan[t] = v;
    __syncthreads();
    for (int d = 1; d < 256; d <<= 1) {
        int val = (t >= d) ? sscan[t - d] : 0;
        __syncthreads();
        sscan[t] += val;
        __syncthreads();
    }
    int ex = sscan[t] - v;
    lcur[2 * t] = ex; lcur[2 * t + 1] = ex + d0;
    __syncthreads();
    int nloc = NN - nbase; if (nloc > NPB) nloc = NPB;
    for (int ln = t; ln < nloc; ln += 256) {
        off[nbase + ln] = base + lcur[ln];
        deg[nbase + ln] = ldeg[ln];
    }
    __syncthreads();
    for (int i = t; i < cntb; i += 256) {
        uint2 pr = pairs[base + i];
        int p = atomicAdd(&lcur[pr.y - nbase], 1);
        csr[base + p] = (int)pr.x;
    }
}

// ---- agg1: mean of x-part of axb over neighbors -> axb cols 0..127 ----
// wave per node; 4 subwaves x 4-deep unroll = 16 gathers in flight
__global__ void k_agg1(const unsigned int* axb_u, const int* off, const int* deg,
                       const int* csr, unsigned int* axb_w) {
    int wid = (blockIdx.x * 256 + threadIdx.x) >> 6;
    if (wid >= NN) return;
    int lane = threadIdx.x & 63;
    int sub = lane >> 4, l16 = lane & 15;
    int start = off[wid], d = deg[wid];
    const unsigned int* gp = axb_u + 64 + (l16 << 2);
    float a[8] = {0.f, 0.f, 0.f, 0.f, 0.f, 0.f, 0.f, 0.f};
    int j = sub;
    for (; j + 12 < d; j += 16) {
        int n0 = csr[start + j];
        int n1 = csr[start + j + 4];
        int n2 = csr[start + j + 8];
        int n3 = csr[start + j + 12];
        uint4 u0 = *(const uint4*)(gp + (size_t)n0 * 128);
        uint4 u1 = *(const uint4*)(gp + (size_t)n1 * 128);
        uint4 u2 = *(const uint4*)(gp + (size_t)n2 * 128);
        uint4 u3 = *(const uint4*)(gp + (size_t)n3 * 128);
        addp(a, u0); addp(a, u1); addp(a, u2); addp(a, u3);
    }
    for (; j < d; j += 4) {
        int nb = csr[start + j];
        uint4 u = *(const uint4*)(gp + (size_t)nb * 128);
        addp(a, u);
    }
#pragma unroll
    for (int i = 0; i < 8; i++) {
        a[i] += __shfl_xor(a[i], 16, 64);
        a[i] += __shfl_xor(a[i], 32, 64);
    }
    if (sub == 0) {
        float inv = 1.0f / (float)(d > 0 ? d : 1);
        uint4 o;
        o.x = pack_bf16(a[0] * inv, a[1] * inv);
        o.y = pack_bf16(a[2] * inv, a[3] * inv);
        o.z = pack_bf16(a[4] * inv, a[5] * inv);
        o.w = pack_bf16(a[6] * inv, a[7] * inv);
        *(uint4*)(axb_w + (size_t)wid * 128 + (l16 << 2)) = o;
    }
}

// ---- agg2: out += mean of g over neighbors ----
__global__ void k_agg2(const unsigned int* g, const int* off, const int* deg,
                       const int* csr, float* out) {
    int wid = (blockIdx.x * 256 + threadIdx.x) >> 6;
    if (wid >= NN) return;
    int lane = threadIdx.x & 63;
    int sub = lane >> 4, l16 = lane & 15;
    int start = off[wid], d = deg[wid];
    const unsigned int* gp = g + (l16 << 2);
    float a[8] = {0.f, 0.f, 0.f, 0.f, 0.f, 0.f, 0.f, 0.f};
    int j = sub;
    for (; j + 12 < d; j += 16) {
        int n0 = csr[start + j];
        int n1 = csr[start + j + 4];
        int n2 = csr[start + j + 8];
        int n3 = csr[start + j + 12];
        uint4 u0 = *(const uint4*)(gp + (size_t)n0 * 64);
        uint4 u1 = *(const uint4*)(gp + (size_t)n1 * 64);
        uint4 u2 = *(const uint4*)(gp + (size_t)n2 * 64);
        uint4 u3 = *(const uint4*)(gp + (size_t)n3 * 64);
        addp(a, u0); addp(a, u1); addp(a, u2); addp(a, u3);
    }
    for (; j < d; j += 4) {
        int nb = csr[start + j];
        uint4 u = *(const uint4*)(gp + (size_t)nb * 64);
        addp(a, u);
    }
#pragma unroll
    for (int i = 0; i < 8; i++) {
        a[i] += __shfl_xor(a[i], 16, 64);
        a[i] += __shfl_xor(a[i], 32, 64);
    }
    if (sub == 0) {
        float inv = 1.0f / (float)(d > 0 ? d : 1);
        float4* po = (float4*)(out + (size_t)wid * 128) + (l16 << 1);
        float4 c0 = po[0], c1 = po[1];
        c0.x += a[0] * inv; c0.y += a[1] * inv; c0.z += a[2] * inv; c0.w += a[3] * inv;
        c1.x += a[4] * inv; c1.y += a[5] * inv; c1.z += a[6] * inv; c1.w += a[7] * inv;
        po[0] = c0; po[1] = c1;
    }
}

// ---- GEMM helpers ----
__device__ __forceinline__ void loadA(short8 afr[2][8], const unsigned short* A,
                                      int base, int mrow, int quad) {
#pragma unroll
    for (int kk = 0; kk < 8; kk++) {
        afr[0][kk] = *(const short8*)(A + (size_t)(base + mrow) * 256 + kk * 32 + quad * 8);
        afr[1][kk] = *(const short8*)(A + (size_t)(base + 16 + mrow) * 256 + kk * 32 + quad * 8);
    }
}
__device__ __forceinline__ void mfmaAcc(float4v acc[2][16], short8 afr[2][8],
                                        const unsigned short* Bs, int mrow, int quad) {
#pragma unroll
    for (int h = 0; h < 2; h++)
#pragma unroll
        for (int ct = 0; ct < 16; ct++) acc[h][ct] = (float4v)(0.0f);
#pragma unroll
    for (int kk = 0; kk < 8; kk++) {
        int koff = kk * 32 + quad * 8;
#pragma unroll
        for (int ct = 0; ct < 16; ct++) {
            short8 b = *(const short8*)(Bs + (ct * 16 + mrow) * 256 + koff);
            acc[0][ct] = __builtin_amdgcn_mfma_f32_16x16x32_bf16(afr[0][kk], b, acc[0][ct], 0, 0, 0);
            acc[1][ct] = __builtin_amdgcn_mfma_f32_16x16x32_bf16(afr[1][kk], b, acc[1][ct], 0, 0, 0);
        }
    }
}

// ---- persistent GEMM1: relu(A@wb1^T + b1) -> H ; A-prefetch double-buffer ----
__global__ __launch_bounds__(256, 1) void k_gemm1(const unsigned short* A, const unsigned short* wb,
                                                  const float* b1, unsigned short* H) {
    __shared__ unsigned short Bs[256 * 256];   // 128 KB
    int t = threadIdx.x;
    {
        const short8* src = (const short8*)wb;
        short8* dst = (short8*)Bs;
#pragma unroll
        for (int i = 0; i < 32; i++) dst[i * 256 + t] = src[i * 256 + t];
    }
    int wv = t >> 6, lane = t & 63;
    int mrow = lane & 15, quad = lane >> 4;
    float bias[16];
#pragma unroll
    for (int ct = 0; ct < 16; ct++) bias[ct] = b1[ct * 16 + mrow];
    short8 afrA[2][8], afrB[2][8];
    int chunk = blockIdx.x;
    int base = chunk * 128 + wv * 32;
    if (base < NN) loadA(afrA, A, base, mrow, quad);
    __syncthreads();
    bool useA = true;
    while (chunk < NCHUNK) {
        int cn = chunk + 256;
        int bn = cn * 128 + wv * 32;
        if (cn < NCHUNK && bn < NN) {
            if (useA) loadA(afrB, A, bn, mrow, quad);
            else      loadA(afrA, A, bn, mrow, quad);
        }
        if (base < NN) {
            float4v acc[2][16];
            mfmaAcc(acc, useA ? afrA : afrB, Bs, mrow, quad);
#pragma unroll
            for (int ct = 0; ct < 16; ct++) {
                int col = ct * 16 + mrow;
#pragma unroll
                for (int h = 0; h < 2; h++)
#pragma unroll
                    for (int r = 0; r < 4; r++) {
                        int node = base + h * 16 + quad * 4 + r;
                        float v = acc[h][ct][r] + bias[ct];
                        H[(size_t)node * 256 + col] = f2bf(fmaxf(v, 0.f));
                    }
            }
        }
        chunk = cn; base = bn; useA = !useA;
    }
}

// ---- persistent GEMM2: cols 0..127 -> g bf16, cols 128..255 -> out f32 (+b2) ----
__global__ __launch_bounds__(256, 1) void k_gemm2(const unsigned short* A, const unsigned short* wb,
                                                  const float* b2, unsigned short* g, float* out) {
    __shared__ unsigned short Bs[256 * 256];   // 128 KB
    int t = threadIdx.x;
    {
        const short8* src = (const short8*)wb;
        short8* dst = (short8*)Bs;
#pragma unroll
        for (int i = 0; i < 32; i++) dst[i * 256 + t] = src[i * 256 + t];
    }
    int wv = t >> 6, lane = t & 63;
    int mrow = lane & 15, quad = lane >> 4;
    float bias[8];
#pragma unroll
    for (int i = 0; i < 8; i++) bias[i] = b2[i * 16 + mrow];
    short8 afrA[2][8], afrB[2][8];
    int chunk = blockIdx.x;
    int base = chunk * 128 + wv * 32;
    if (base < NN) loadA(afrA, A, base, mrow, quad);
    __syncthreads();
    bool useA = true;
    while (chunk < NCHUNK) {
        int cn = chunk + 256;
        int bn = cn * 128 + wv * 32;
        if (cn < NCHUNK && bn < NN) {
            if (useA) loadA(afrB, A, bn, mrow, quad);
            else      loadA(afrA, A, bn, mrow, quad);
        }
        if (base < NN) {
            float4v acc[2][16];
            mfmaAcc(acc, useA ? afrA : afrB, Bs, mrow, quad);
#pragma unroll
            for (int ct = 0; ct < 16; ct++) {
                int col = ct * 16 + mrow;
#pragma unroll
                for (int h = 0; h < 2; h++)
#pragma unroll
                    for (int r = 0; r < 4; r++) {
                        int node = base + h * 16 + quad * 4 + r;
                        float v = acc[h][ct][r];
                        if (ct < 8) g[(size_t)node * 128 + col] = f2bf(v);
                        else        out[(size_t)node * 128 + (col - 128)] = v + bias[ct - 8];
                    }
            }
        }
        chunk = cn; base = bn; useA = !useA;
    }
}

extern "C" void kernel_launch(void* const* d_in, const int* in_sizes, int n_in,
                              void* d_out, int out_size, void* d_ws, size_t ws_size,
                              hipStream_t stream) {
    const float* x   = (const float*)d_in[0];
    const int*   ei  = (const int*)d_in[1];
    const float* W1l = (const float*)d_in[2];
    const float* b1  = (const float*)d_in[3];
    const float* W1r = (const float*)d_in[4];
    const float* W2l = (const float*)d_in[5];
    const float* b2  = (const float*)d_in[6];
    const float* W2r = (const float*)d_in[7];
    float* out = (float*)d_out;

    char* p = (char*)d_ws;
    unsigned int* axb = (unsigned int*)p; p += (size_t)NN * 256 * 2;  // [agg(128) | x(128)] bf16
    unsigned short* h = (unsigned short*)p; p += (size_t)NN * 256 * 2;
    unsigned int* g   = (unsigned int*)p;  p += (size_t)NN * 128 * 2;
    unsigned short* wb1 = (unsigned short*)p; p += 65536 * 2;
    unsigned short* wb2 = (unsigned short*)p; p += 65536 * 2;
    int* deg  = (int*)p; p += (size_t)NN * 4;
    int* off  = (int*)p; p += (size_t)NN * 4;
    int* csr  = (int*)p; p += (size_t)NE * 4;
    int* bcnt = (int*)p; p += NB * 4;
    int* boff = (int*)p; p += (NB + 1) * 4;
    int* bcur = (int*)p; p += NB * 4;
    if (ws_size < (size_t)(p - (char*)d_ws)) return;
    uint2* pairs = (uint2*)h;   // overlay: pairs dead before gemm1 writes h

    hipMemsetAsync(bcnt, 0, NB * 4, stream);
    k_prep<<<25384, 256, 0, stream>>>(x, W1l, W1r, W2l, W2r, ei, axb, wb1, wb2, bcnt);
    k_bscan<<<1, NB, 0, stream>>>(bcnt, boff, bcur);
    k_bscatter<<<NCH, 256, 0, stream>>>(ei, bcur, pairs);
    k_build<<<NB, 256, 0, stream>>>(pairs, boff, off, deg, csr);
    k_agg1<<<NN * 64 / 256, 256, 0, stream>>>(axb, off, deg, csr, axb);
    k_gemm1<<<256, 256, 0, stream>>>((const unsigned short*)axb, wb1, b1, h);
    k_gemm2<<<256, 256, 0, stream>>>(h, wb2, b2, (unsigned short*)g, out);
    k_agg2<<<25000, 256, 0, stream>>>(g, off, deg, csr, out);
}

// Round 5
// 375.343 us; speedup vs baseline: 1.0933x; 1.0933x over previous
//
#include <hip/hip_runtime.h>
#include <hip/hip_bf16.h>

#define NN 100000
#define NE 1600000
#define NCHUNK ((NN + 127) / 128)   // 782 (gemm row chunks of 128)
#define NPB 512                      // nodes per bucket (pow2, shift 9)
#define NB 256                       // bucket slots (196 active)
#define CHUNK 8192                   // edges per bscatter block
#define NCH ((NE + CHUNK - 1) / CHUNK)  // 196

typedef __attribute__((ext_vector_type(8))) short short8;
typedef __attribute__((ext_vector_type(4))) float float4v;
typedef __attribute__((ext_vector_type(2))) float float2v;

__device__ __forceinline__ unsigned short f2bf(float f) {
    unsigned int b = __float_as_uint(f);
    return (unsigned short)((b + 0x7fffu + ((b >> 16) & 1u)) >> 16);
}
__device__ __forceinline__ unsigned int pack_bf16(float lo, float hi) {
    return (unsigned int)f2bf(lo) | ((unsigned int)f2bf(hi) << 16);
}
__device__ __forceinline__ float bflo(unsigned int u) { return __uint_as_float(u << 16); }
__device__ __forceinline__ float bfhi(unsigned int u) { return __uint_as_float(u & 0xffff0000u); }

__device__ __forceinline__ void addp(float* a, uint4 u) {
    a[0] += bflo(u.x); a[1] += bfhi(u.x);
    a[2] += bflo(u.y); a[3] += bfhi(u.y);
    a[4] += bflo(u.z); a[5] += bfhi(u.z);
    a[6] += bflo(u.w); a[7] += bfhi(u.w);
}
// 8 fp8 (e4m3) in a uint2 -> accumulate into a[0..7]
__device__ __forceinline__ void addp8(float* a, uint2 u) {
    float2v f;
    f = __builtin_amdgcn_cvt_pk_f32_fp8(u.x, false); a[0] += f.x; a[1] += f.y;
    f = __builtin_amdgcn_cvt_pk_f32_fp8(u.x, true);  a[2] += f.x; a[3] += f.y;
    f = __builtin_amdgcn_cvt_pk_f32_fp8(u.y, false); a[4] += f.x; a[5] += f.y;
    f = __builtin_amdgcn_cvt_pk_f32_fp8(u.y, true);  a[6] += f.x; a[7] += f.y;
}
__device__ __forceinline__ unsigned char f2fp8(float v) {
    int r = __builtin_amdgcn_cvt_pk_fp8_f32(v, v, 0, false);
    return (unsigned char)(r & 0xff);
}

// ---- fused prep: xconv (blocks 0..24999), wconv (25000..25127), bcount (25128..25383) ----
__global__ void k_prep(const float* x, const float* W1l, const float* W1r,
                       const float* W2l, const float* W2r, const int* ei,
                       unsigned int* axb_u, unsigned short* wb1, unsigned short* wb2,
                       int* bcnt) {
    __shared__ int hh[NB];
    int b = blockIdx.x, t = threadIdx.x;
    if (b < 25000) {
        int tt = b * 256 + t;
        int node = tt >> 6, i = tt & 63;
        float2 v = ((const float2*)x)[tt];
        axb_u[(size_t)node * 128 + 64 + i] = pack_bf16(v.x, v.y);
    } else if (b < 25128) {
        int i = (b - 25000) * 256 + t;        // < 32768
        int r1 = i >> 7, c1 = i & 127;        // W1l/W1r are 256x128
        wb1[r1 * 256 + c1]       = f2bf(W1l[i]);
        wb1[r1 * 256 + 128 + c1] = f2bf(W1r[i]);
        wb2[i]         = f2bf(W2l[i]);        // 128x256, k contiguous
        wb2[32768 + i] = f2bf(W2r[i]);
    } else {
        hh[t] = 0;
        __syncthreads();
        int e0 = (b - 25128) * 6250;          // 256 * 6250 = NE exactly
        for (int e = e0 + t; e < e0 + 6250; e += 256)
            atomicAdd(&hh[ei[NE + e] >> 9], 1);
        __syncthreads();
        if (hh[t]) atomicAdd(&bcnt[t], hh[t]);
    }
}

__global__ void k_bscan(const int* bcnt, int* boff, int* bcur) {
    __shared__ int s[NB];
    int t = threadIdx.x;
    int v = bcnt[t];
    s[t] = v;
    __syncthreads();
    for (int d = 1; d < NB; d <<= 1) {
        int val = (t >= d) ? s[t - d] : 0;
        __syncthreads();
        s[t] += val;
        __syncthreads();
    }
    boff[t + 1] = s[t];
    if (t == 0) boff[0] = 0;
    bcur[t] = s[t] - v;   // exclusive
}

__global__ __launch_bounds__(256) void k_bscatter(const int* ei, int* bcur, uint2* pairs) {
    __shared__ uint2 buf[CHUNK];       // 64 KB
    __shared__ int cnt[NB];
    __shared__ int lbase[NB];
    __shared__ int lcur[NB];
    __shared__ int gpos[NB];
    int t = threadIdx.x;
    int e0 = blockIdx.x * CHUNK;
    int nedge = NE - e0; if (nedge > CHUNK) nedge = CHUNK;
    cnt[t] = 0;
    __syncthreads();
    for (int i = t; i < nedge; i += 256)
        atomicAdd(&cnt[ei[NE + e0 + i] >> 9], 1);
    __syncthreads();
    int v = cnt[t];
    lcur[t] = v;
    __syncthreads();
    for (int d = 1; d < NB; d <<= 1) {
        int val = (t >= d) ? lcur[t - d] : 0;
        __syncthreads();
        lcur[t] += val;
        __syncthreads();
    }
    lbase[t] = lcur[t] - v;
    gpos[t] = atomicAdd(&bcur[t], v);
    __syncthreads();
    lcur[t] = lbase[t];
    __syncthreads();
    for (int i = t; i < nedge; i += 256) {
        int r = ei[e0 + i], c = ei[NE + e0 + i];
        int b = c >> 9;
        int p = atomicAdd(&lcur[b], 1);
        buf[p] = make_uint2((unsigned)r, (unsigned)c);
    }
    __syncthreads();
    // coalesced flush: wave wv handles buckets wv, wv+4, ...; lanes stride inside
    int wv = t >> 6, lane = t & 63;
    for (int b = wv; b < NB; b += 4) {
        int n = cnt[b], lb = lbase[b], gp = gpos[b];
        for (int i = lane; i < n; i += 64)
            pairs[gp + i] = buf[lb + i];
    }
}

__global__ __launch_bounds__(256) void k_build(const uint2* pairs, const int* boff,
                                               int* off, int* deg, int* csr) {
    __shared__ int ldeg[NPB];
    __shared__ int lcur[NPB];
    __shared__ int sscan[256];
    int b = blockIdx.x;
    int nbase = b * NPB;
    if (nbase >= NN) return;
    int t = threadIdx.x;
    int base = boff[b], cntb = boff[b + 1] - base;
    ldeg[t] = 0; ldeg[t + 256] = 0;
    __syncthreads();
    for (int i = t; i < cntb; i += 256) {
        uint2 pr = pairs[base + i];
        atomicAdd(&ldeg[pr.y - nbase], 1);
    }
    __syncthreads();
    int d0 = ldeg[2 * t], d1 = ldeg[2 * t + 1];
    int v = d0 + d1;
    sscan[t] = v;
    __syncthreads();
    for (int d = 1; d < 256; d <<= 1) {
        int val = (t >= d) ? sscan[t - d] : 0;
        __syncthreads();
        sscan[t] += val;
        __syncthreads();
    }
    int ex = sscan[t] - v;
    lcur[2 * t] = ex; lcur[2 * t + 1] = ex + d0;
    __syncthreads();
    int nloc = NN - nbase; if (nloc > NPB) nloc = NPB;
    for (int ln = t; ln < nloc; ln += 256) {
        off[nbase + ln] = base + lcur[ln];
        deg[nbase + ln] = ldeg[ln];
    }
    __syncthreads();
    for (int i = t; i < cntb; i += 256) {
        uint2 pr = pairs[base + i];
        int p = atomicAdd(&lcur[pr.y - nbase], 1);
        csr[base + p] = (int)pr.x;
    }
}

// ---- agg1: mean of x-part of axb over neighbors -> axb cols 0..127 (bf16) ----
__global__ void k_agg1(const unsigned int* axb_u, const int* off, const int* deg,
                       const int* csr, unsigned int* axb_w) {
    int wid = (blockIdx.x * 256 + threadIdx.x) >> 6;
    if (wid >= NN) return;
    int lane = threadIdx.x & 63;
    int sub = lane >> 4, l16 = lane & 15;
    int start = off[wid], d = deg[wid];
    const unsigned int* gp = axb_u + 64 + (l16 << 2);
    float a[8] = {0.f, 0.f, 0.f, 0.f, 0.f, 0.f, 0.f, 0.f};
    int j = sub;
    for (; j + 4 < d; j += 8) {
        int n0 = csr[start + j];
        int n1 = csr[start + j + 4];
        uint4 u0 = *(const uint4*)(gp + (size_t)n0 * 128);
        uint4 u1 = *(const uint4*)(gp + (size_t)n1 * 128);
        addp(a, u0); addp(a, u1);
    }
    if (j < d) {
        int nb = csr[start + j];
        uint4 u = *(const uint4*)(gp + (size_t)nb * 128);
        addp(a, u);
    }
#pragma unroll
    for (int i = 0; i < 8; i++) {
        a[i] += __shfl_xor(a[i], 16, 64);
        a[i] += __shfl_xor(a[i], 32, 64);
    }
    if (sub == 0) {
        float inv = 1.0f / (float)(d > 0 ? d : 1);
        uint4 o;
        o.x = pack_bf16(a[0] * inv, a[1] * inv);
        o.y = pack_bf16(a[2] * inv, a[3] * inv);
        o.z = pack_bf16(a[4] * inv, a[5] * inv);
        o.w = pack_bf16(a[6] * inv, a[7] * inv);
        *(uint4*)(axb_w + (size_t)wid * 128 + (l16 << 2)) = o;
    }
}

// ---- agg2: out += mean of g (fp8 e4m3) over neighbors ----
__global__ void k_agg2(const uint2* g, const int* off, const int* deg,
                       const int* csr, float* out) {
    int wid = (blockIdx.x * 256 + threadIdx.x) >> 6;
    if (wid >= NN) return;
    int lane = threadIdx.x & 63;
    int sub = lane >> 4, l16 = lane & 15;
    int start = off[wid], d = deg[wid];
    const uint2* gp = g + l16;   // row stride = 16 uint2 (128 B)
    float a[8] = {0.f, 0.f, 0.f, 0.f, 0.f, 0.f, 0.f, 0.f};
    int j = sub;
    for (; j + 4 < d; j += 8) {
        int n0 = csr[start + j];
        int n1 = csr[start + j + 4];
        uint2 u0 = gp[(size_t)n0 * 16];
        uint2 u1 = gp[(size_t)n1 * 16];
        addp8(a, u0); addp8(a, u1);
    }
    if (j < d) {
        int nb = csr[start + j];
        uint2 u = gp[(size_t)nb * 16];
        addp8(a, u);
    }
#pragma unroll
    for (int i = 0; i < 8; i++) {
        a[i] += __shfl_xor(a[i], 16, 64);
        a[i] += __shfl_xor(a[i], 32, 64);
    }
    if (sub == 0) {
        float inv = 1.0f / (float)(d > 0 ? d : 1);
        float4* po = (float4*)(out + (size_t)wid * 128) + (l16 << 1);
        float4 c0 = po[0], c1 = po[1];
        c0.x += a[0] * inv; c0.y += a[1] * inv; c0.z += a[2] * inv; c0.w += a[3] * inv;
        c1.x += a[4] * inv; c1.y += a[5] * inv; c1.z += a[6] * inv; c1.w += a[7] * inv;
        po[0] = c0; po[1] = c1;
    }
}

// ---- persistent GEMM1: relu(A@wb1^T + b1) -> H (bf16) ----
__global__ __launch_bounds__(256, 1) void k_gemm1(const unsigned short* A, const unsigned short* wb,
                                                  const float* b1, unsigned short* H) {
    __shared__ unsigned short Bs[256 * 256];   // 128 KB
    int t = threadIdx.x;
    {
        const short8* src = (const short8*)wb;
        short8* dst = (short8*)Bs;
#pragma unroll
        for (int i = 0; i < 32; i++) dst[i * 256 + t] = src[i * 256 + t];
    }
    __syncthreads();
    int wv = t >> 6, lane = t & 63;
    int mrow = lane & 15, quad = lane >> 4;
    float bias[16];
#pragma unroll
    for (int ct = 0; ct < 16; ct++) bias[ct] = b1[ct * 16 + mrow];
    for (int chunk = blockIdx.x; chunk < NCHUNK; chunk += gridDim.x) {
        int base = chunk * 128 + wv * 32;
        if (base >= NN) continue;
        short8 afr[2][8];
#pragma unroll
        for (int kk = 0; kk < 8; kk++) {
            afr[0][kk] = *(const short8*)(A + (size_t)(base + mrow) * 256 + kk * 32 + quad * 8);
            afr[1][kk] = *(const short8*)(A + (size_t)(base + 16 + mrow) * 256 + kk * 32 + quad * 8);
        }
        float4v acc[2][16];
#pragma unroll
        for (int h = 0; h < 2; h++)
#pragma unroll
            for (int ct = 0; ct < 16; ct++) acc[h][ct] = (float4v)(0.0f);
#pragma unroll
        for (int kk = 0; kk < 8; kk++) {
            int koff = kk * 32 + quad * 8;
#pragma unroll
            for (int ct = 0; ct < 16; ct++) {
                short8 b = *(const short8*)(Bs + (ct * 16 + mrow) * 256 + koff);
                acc[0][ct] = __builtin_amdgcn_mfma_f32_16x16x32_bf16(afr[0][kk], b, acc[0][ct], 0, 0, 0);
                acc[1][ct] = __builtin_amdgcn_mfma_f32_16x16x32_bf16(afr[1][kk], b, acc[1][ct], 0, 0, 0);
            }
        }
#pragma unroll
        for (int ct = 0; ct < 16; ct++) {
            int col = ct * 16 + mrow;
#pragma unroll
            for (int h = 0; h < 2; h++)
#pragma unroll
                for (int r = 0; r < 4; r++) {
                    int node = base + h * 16 + quad * 4 + r;
                    float v = acc[h][ct][r] + bias[ct];
                    H[(size_t)node * 256 + col] = f2bf(fmaxf(v, 0.f));
                }
        }
    }
}

// ---- persistent GEMM2: cols 0..127 -> g (fp8), cols 128..255 -> out f32 (+b2) ----
__global__ __launch_bounds__(256, 1) void k_gemm2(const unsigned short* A, const unsigned short* wb,
                                                  const float* b2, unsigned char* g, float* out) {
    __shared__ unsigned short Bs[256 * 256];   // 128 KB
    int t = threadIdx.x;
    {
        const short8* src = (const short8*)wb;
        short8* dst = (short8*)Bs;
#pragma unroll
        for (int i = 0; i < 32; i++) dst[i * 256 + t] = src[i * 256 + t];
    }
    __syncthreads();
    int wv = t >> 6, lane = t & 63;
    int mrow = lane & 15, quad = lane >> 4;
    float bias[8];
#pragma unroll
    for (int i = 0; i < 8; i++) bias[i] = b2[i * 16 + mrow];
    for (int chunk = blockIdx.x; chunk < NCHUNK; chunk += gridDim.x) {
        int base = chunk * 128 + wv * 32;
        if (base >= NN) continue;
        short8 afr[2][8];
#pragma unroll
        for (int kk = 0; kk < 8; kk++) {
            afr[0][kk] = *(const short8*)(A + (size_t)(base + mrow) * 256 + kk * 32 + quad * 8);
            afr[1][kk] = *(const short8*)(A + (size_t)(base + 16 + mrow) * 256 + kk * 32 + quad * 8);
        }
        float4v acc[2][16];
#pragma unroll
        for (int h = 0; h < 2; h++)
#pragma unroll
            for (int ct = 0; ct < 16; ct++) acc[h][ct] = (float4v)(0.0f);
#pragma unroll
        for (int kk = 0; kk < 8; kk++) {
            int koff = kk * 32 + quad * 8;
#pragma unroll
            for (int ct = 0; ct < 16; ct++) {
                short8 b = *(const short8*)(Bs + (ct * 16 + mrow) * 256 + koff);
                acc[0][ct] = __builtin_amdgcn_mfma_f32_16x16x32_bf16(afr[0][kk], b, acc[0][ct], 0, 0, 0);
                acc[1][ct] = __builtin_amdgcn_mfma_f32_16x16x32_bf16(afr[1][kk], b, acc[1][ct], 0, 0, 0);
            }
        }
#pragma unroll
        for (int ct = 0; ct < 16; ct++) {
            int col = ct * 16 + mrow;
#pragma unroll
            for (int h = 0; h < 2; h++)
#pragma unroll
                for (int r = 0; r < 4; r++) {
                    int node = base + h * 16 + quad * 4 + r;
                    float v = acc[h][ct][r];
                    if (ct < 8) g[(size_t)node * 128 + col] = f2fp8(v);
                    else        out[(size_t)node * 128 + (col - 128)] = v + bias[ct - 8];
                }
        }
    }
}

extern "C" void kernel_launch(void* const* d_in, const int* in_sizes, int n_in,
                              void* d_out, int out_size, void* d_ws, size_t ws_size,
                              hipStream_t stream) {
    const float* x   = (const float*)d_in[0];
    const int*   ei  = (const int*)d_in[1];
    const float* W1l = (const float*)d_in[2];
    const float* b1  = (const float*)d_in[3];
    const float* W1r = (const float*)d_in[4];
    const float* W2l = (const float*)d_in[5];
    const float* b2  = (const float*)d_in[6];
    const float* W2r = (const float*)d_in[7];
    float* out = (float*)d_out;

    char* p = (char*)d_ws;
    unsigned int* axb = (unsigned int*)p; p += (size_t)NN * 256 * 2;  // [agg(128) | x(128)] bf16
    unsigned short* h = (unsigned short*)p; p += (size_t)NN * 256 * 2;
    unsigned char* g  = (unsigned char*)p; p += (size_t)NN * 128;     // fp8 e4m3
    unsigned short* wb1 = (unsigned short*)p; p += 65536 * 2;
    unsigned short* wb2 = (unsigned short*)p; p += 65536 * 2;
    int* deg  = (int*)p; p += (size_t)NN * 4;
    int* off  = (int*)p; p += (size_t)NN * 4;
    int* csr  = (int*)p; p += (size_t)NE * 4;
    int* bcnt = (int*)p; p += NB * 4;
    int* boff = (int*)p; p += (NB + 1) * 4;
    int* bcur = (int*)p; p += NB * 4;
    if (ws_size < (size_t)(p - (char*)d_ws)) return;
    uint2* pairs = (uint2*)h;   // overlay: pairs dead before gemm1 writes h

    hipMemsetAsync(bcnt, 0, NB * 4, stream);
    k_prep<<<25384, 256, 0, stream>>>(x, W1l, W1r, W2l, W2r, ei, axb, wb1, wb2, bcnt);
    k_bscan<<<1, NB, 0, stream>>>(bcnt, boff, bcur);
    k_bscatter<<<NCH, 256, 0, stream>>>(ei, bcur, pairs);
    k_build<<<NB, 256, 0, stream>>>(pairs, boff, off, deg, csr);
    k_agg1<<<NN * 64 / 256, 256, 0, stream>>>(axb, off, deg, csr, axb);
    k_gemm1<<<256, 256, 0, stream>>>((const unsigned short*)axb, wb1, b1, h);
    k_gemm2<<<256, 256, 0, stream>>>(h, wb2, b2, g, out);
    k_agg2<<<25000, 256, 0, stream>>>((const uint2*)g, off, deg, csr, out);
}

// Round 6
// 367.545 us; speedup vs baseline: 1.1165x; 1.0212x over previous
//
#include <hip/hip_runtime.h>
#include <hip/hip_bf16.h>

#define NN 100000
#define NE 1600000
#define NCHUNK ((NN + 127) / 128)   // 782 (gemm row chunks of 128)
#define NPB 512                      // nodes per bucket (pow2, shift 9)
#define NB 256                       // bucket slots (196 active)
#define CHUNK 8192                   // edges per bscatter block
#define NCH ((NE + CHUNK - 1) / CHUNK)  // 196

typedef __attribute__((ext_vector_type(8))) short short8;
typedef __attribute__((ext_vector_type(4))) float float4v;
typedef __attribute__((ext_vector_type(2))) float float2v;

__device__ __forceinline__ unsigned short f2bf(float f) {
    unsigned int b = __float_as_uint(f);
    return (unsigned short)((b + 0x7fffu + ((b >> 16) & 1u)) >> 16);
}
__device__ __forceinline__ unsigned int pack_bf16(float lo, float hi) {
    return (unsigned int)f2bf(lo) | ((unsigned int)f2bf(hi) << 16);
}
__device__ __forceinline__ float bflo(unsigned int u) { return __uint_as_float(u << 16); }
__device__ __forceinline__ float bfhi(unsigned int u) { return __uint_as_float(u & 0xffff0000u); }

__device__ __forceinline__ void addp(float* a, uint4 u) {
    a[0] += bflo(u.x); a[1] += bfhi(u.x);
    a[2] += bflo(u.y); a[3] += bfhi(u.y);
    a[4] += bflo(u.z); a[5] += bfhi(u.z);
    a[6] += bflo(u.w); a[7] += bfhi(u.w);
}
// 8 fp8 (e4m3) in a uint2 -> accumulate into a[0..7]
__device__ __forceinline__ void addp8(float* a, uint2 u) {
    float2v f;
    f = __builtin_amdgcn_cvt_pk_f32_fp8(u.x, false); a[0] += f.x; a[1] += f.y;
    f = __builtin_amdgcn_cvt_pk_f32_fp8(u.x, true);  a[2] += f.x; a[3] += f.y;
    f = __builtin_amdgcn_cvt_pk_f32_fp8(u.y, false); a[4] += f.x; a[5] += f.y;
    f = __builtin_amdgcn_cvt_pk_f32_fp8(u.y, true);  a[6] += f.x; a[7] += f.y;
}
__device__ __forceinline__ unsigned char f2fp8(float v) {
    int r = __builtin_amdgcn_cvt_pk_fp8_f32(v, v, 0, false);
    return (unsigned char)(r & 0xff);
}
__device__ __forceinline__ unsigned short pack2fp8(float lo, float hi) {
    int r = __builtin_amdgcn_cvt_pk_fp8_f32(lo, hi, 0, false);
    return (unsigned short)(r & 0xffff);
}

// ---- fused prep: xconv (blocks 0..24999), wconv (25000..25127), bcount (25128..25383) ----
__global__ void k_prep(const float* x, const float* W1l, const float* W1r,
                       const float* W2l, const float* W2r, const int* ei,
                       unsigned int* axb_u, unsigned short* xf8, unsigned short* wb1,
                       unsigned short* wb2, int* bcnt) {
    __shared__ int hh[NB];
    int b = blockIdx.x, t = threadIdx.x;
    if (b < 25000) {
        int tt = b * 256 + t;
        int node = tt >> 6, i = tt & 63;
        float2 v = ((const float2*)x)[tt];
        axb_u[(size_t)node * 128 + 64 + i] = pack_bf16(v.x, v.y);
        xf8[(size_t)node * 64 + i] = pack2fp8(v.x, v.y);
    } else if (b < 25128) {
        int i = (b - 25000) * 256 + t;        // < 32768
        int r1 = i >> 7, c1 = i & 127;        // W1l/W1r are 256x128
        wb1[r1 * 256 + c1]       = f2bf(W1l[i]);
        wb1[r1 * 256 + 128 + c1] = f2bf(W1r[i]);
        wb2[i]         = f2bf(W2l[i]);        // 128x256, k contiguous
        wb2[32768 + i] = f2bf(W2r[i]);
    } else {
        hh[t] = 0;
        __syncthreads();
        int e0 = (b - 25128) * 6250;          // 256 * 6250 = NE exactly
        for (int e = e0 + t; e < e0 + 6250; e += 256)
            atomicAdd(&hh[ei[NE + e] >> 9], 1);
        __syncthreads();
        if (hh[t]) atomicAdd(&bcnt[t], hh[t]);
    }
}

__global__ void k_bscan(const int* bcnt, int* boff, int* bcur) {
    __shared__ int s[NB];
    int t = threadIdx.x;
    int v = bcnt[t];
    s[t] = v;
    __syncthreads();
    for (int d = 1; d < NB; d <<= 1) {
        int val = (t >= d) ? s[t - d] : 0;
        __syncthreads();
        s[t] += val;
        __syncthreads();
    }
    boff[t + 1] = s[t];
    if (t == 0) boff[0] = 0;
    bcur[t] = s[t] - v;   // exclusive
}

__global__ __launch_bounds__(256) void k_bscatter(const int* ei, int* bcur, uint2* pairs) {
    __shared__ uint2 buf[CHUNK];       // 64 KB
    __shared__ int cnt[NB];
    __shared__ int lbase[NB];
    __shared__ int lcur[NB];
    __shared__ int gpos[NB];
    int t = threadIdx.x;
    int e0 = blockIdx.x * CHUNK;
    int nedge = NE - e0; if (nedge > CHUNK) nedge = CHUNK;
    cnt[t] = 0;
    __syncthreads();
    for (int i = t; i < nedge; i += 256)
        atomicAdd(&cnt[ei[NE + e0 + i] >> 9], 1);
    __syncthreads();
    int v = cnt[t];
    lcur[t] = v;
    __syncthreads();
    for (int d = 1; d < NB; d <<= 1) {
        int val = (t >= d) ? lcur[t - d] : 0;
        __syncthreads();
        lcur[t] += val;
        __syncthreads();
    }
    lbase[t] = lcur[t] - v;
    gpos[t] = atomicAdd(&bcur[t], v);
    __syncthreads();
    lcur[t] = lbase[t];
    __syncthreads();
    for (int i = t; i < nedge; i += 256) {
        int r = ei[e0 + i], c = ei[NE + e0 + i];
        int b = c >> 9;
        int p = atomicAdd(&lcur[b], 1);
        buf[p] = make_uint2((unsigned)r, (unsigned)c);
    }
    __syncthreads();
    // coalesced flush: wave wv handles buckets wv, wv+4, ...; lanes stride inside
    int wv = t >> 6, lane = t & 63;
    for (int b = wv; b < NB; b += 4) {
        int n = cnt[b], lb = lbase[b], gp = gpos[b];
        for (int i = lane; i < n; i += 64)
            pairs[gp + i] = buf[lb + i];
    }
}

__global__ __launch_bounds__(256) void k_build(const uint2* pairs, const int* boff,
                                               int* off, int* deg, int* csr) {
    __shared__ int ldeg[NPB];
    __shared__ int lcur[NPB];
    __shared__ int sscan[256];
    int b = blockIdx.x;
    int nbase = b * NPB;
    if (nbase >= NN) return;
    int t = threadIdx.x;
    int base = boff[b], cntb = boff[b + 1] - base;
    ldeg[t] = 0; ldeg[t + 256] = 0;
    __syncthreads();
    for (int i = t; i < cntb; i += 256) {
        uint2 pr = pairs[base + i];
        atomicAdd(&ldeg[pr.y - nbase], 1);
    }
    __syncthreads();
    int d0 = ldeg[2 * t], d1 = ldeg[2 * t + 1];
    int v = d0 + d1;
    sscan[t] = v;
    __syncthreads();
    for (int d = 1; d < 256; d <<= 1) {
        int val = (t >= d) ? sscan[t - d] : 0;
        __syncthreads();
        sscan[t] += val;
        __syncthreads();
    }
    int ex = sscan[t] - v;
    lcur[2 * t] = ex; lcur[2 * t + 1] = ex + d0;
    __syncthreads();
    int nloc = NN - nbase; if (nloc > NPB) nloc = NPB;
    for (int ln = t; ln < nloc; ln += 256) {
        off[nbase + ln] = base + lcur[ln];
        deg[nbase + ln] = ldeg[ln];
    }
    __syncthreads();
    for (int i = t; i < cntb; i += 256) {
        uint2 pr = pairs[base + i];
        int p = atomicAdd(&lcur[pr.y - nbase], 1);
        csr[base + p] = (int)pr.x;
    }
}

// ---- agg1: mean of xf8 (fp8) over neighbors -> axb cols 0..127 (bf16) ----
__global__ void k_agg1(const uint2* xf8, const int* off, const int* deg,
                       const int* csr, unsigned int* axb_w) {
    int wid = (blockIdx.x * 256 + threadIdx.x) >> 6;
    if (wid >= NN) return;
    int lane = threadIdx.x & 63;
    int sub = lane >> 4, l16 = lane & 15;
    int start = off[wid], d = deg[wid];
    const uint2* gp = xf8 + l16;   // row stride = 16 uint2 (128 B)
    float a[8] = {0.f, 0.f, 0.f, 0.f, 0.f, 0.f, 0.f, 0.f};
    int j = sub;
    for (; j + 4 < d; j += 8) {
        int n0 = csr[start + j];
        int n1 = csr[start + j + 4];
        uint2 u0 = gp[(size_t)n0 * 16];
        uint2 u1 = gp[(size_t)n1 * 16];
        addp8(a, u0); addp8(a, u1);
    }
    if (j < d) {
        int nb = csr[start + j];
        uint2 u = gp[(size_t)nb * 16];
        addp8(a, u);
    }
#pragma unroll
    for (int i = 0; i < 8; i++) {
        a[i] += __shfl_xor(a[i], 16, 64);
        a[i] += __shfl_xor(a[i], 32, 64);
    }
    if (sub == 0) {
        float inv = 1.0f / (float)(d > 0 ? d : 1);
        uint4 o;
        o.x = pack_bf16(a[0] * inv, a[1] * inv);
        o.y = pack_bf16(a[2] * inv, a[3] * inv);
        o.z = pack_bf16(a[4] * inv, a[5] * inv);
        o.w = pack_bf16(a[6] * inv, a[7] * inv);
        *(uint4*)(axb_w + (size_t)wid * 128 + (l16 << 2)) = o;
    }
}

// ---- agg2: out += mean of g (fp8 e4m3) over neighbors ----
__global__ void k_agg2(const uint2* g, const int* off, const int* deg,
                       const int* csr, float* out) {
    int wid = (blockIdx.x * 256 + threadIdx.x) >> 6;
    if (wid >= NN) return;
    int lane = threadIdx.x & 63;
    int sub = lane >> 4, l16 = lane & 15;
    int start = off[wid], d = deg[wid];
    const uint2* gp = g + l16;   // row stride = 16 uint2 (128 B)
    float a[8] = {0.f, 0.f, 0.f, 0.f, 0.f, 0.f, 0.f, 0.f};
    int j = sub;
    for (; j + 4 < d; j += 8) {
        int n0 = csr[start + j];
        int n1 = csr[start + j + 4];
        uint2 u0 = gp[(size_t)n0 * 16];
        uint2 u1 = gp[(size_t)n1 * 16];
        addp8(a, u0); addp8(a, u1);
    }
    if (j < d) {
        int nb = csr[start + j];
        uint2 u = gp[(size_t)nb * 16];
        addp8(a, u);
    }
#pragma unroll
    for (int i = 0; i < 8; i++) {
        a[i] += __shfl_xor(a[i], 16, 64);
        a[i] += __shfl_xor(a[i], 32, 64);
    }
    if (sub == 0) {
        float inv = 1.0f / (float)(d > 0 ? d : 1);
        float4* po = (float4*)(out + (size_t)wid * 128) + (l16 << 1);
        float4 c0 = po[0], c1 = po[1];
        c0.x += a[0] * inv; c0.y += a[1] * inv; c0.z += a[2] * inv; c0.w += a[3] * inv;
        c1.x += a[4] * inv; c1.y += a[5] * inv; c1.z += a[6] * inv; c1.w += a[7] * inv;
        po[0] = c0; po[1] = c1;
    }
}

// ---- persistent GEMM1: relu(A@wb1^T + b1) -> H (bf16) ----
__global__ __launch_bounds__(256, 1) void k_gemm1(const unsigned short* A, const unsigned short* wb,
                                                  const float* b1, unsigned short* H) {
    __shared__ unsigned short Bs[256 * 256];   // 128 KB
    int t = threadIdx.x;
    {
        const short8* src = (const short8*)wb;
        short8* dst = (short8*)Bs;
#pragma unroll
        for (int i = 0; i < 32; i++) dst[i * 256 + t] = src[i * 256 + t];
    }
    __syncthreads();
    int wv = t >> 6, lane = t & 63;
    int mrow = lane & 15, quad = lane >> 4;
    float bias[16];
#pragma unroll
    for (int ct = 0; ct < 16; ct++) bias[ct] = b1[ct * 16 + mrow];
    for (int chunk = blockIdx.x; chunk < NCHUNK; chunk += gridDim.x) {
        int base = chunk * 128 + wv * 32;
        if (base >= NN) continue;
        short8 afr[2][8];
#pragma unroll
        for (int kk = 0; kk < 8; kk++) {
            afr[0][kk] = *(const short8*)(A + (size_t)(base + mrow) * 256 + kk * 32 + quad * 8);
            afr[1][kk] = *(const short8*)(A + (size_t)(base + 16 + mrow) * 256 + kk * 32 + quad * 8);
        }
        float4v acc[2][16];
#pragma unroll
        for (int h = 0; h < 2; h++)
#pragma unroll
            for (int ct = 0; ct < 16; ct++) acc[h][ct] = (float4v)(0.0f);
#pragma unroll
        for (int kk = 0; kk < 8; kk++) {
            int koff = kk * 32 + quad * 8;
#pragma unroll
            for (int ct = 0; ct < 16; ct++) {
                short8 b = *(const short8*)(Bs + (ct * 16 + mrow) * 256 + koff);
                acc[0][ct] = __builtin_amdgcn_mfma_f32_16x16x32_bf16(afr[0][kk], b, acc[0][ct], 0, 0, 0);
                acc[1][ct] = __builtin_amdgcn_mfma_f32_16x16x32_bf16(afr[1][kk], b, acc[1][ct], 0, 0, 0);
            }
        }
#pragma unroll
        for (int ct = 0; ct < 16; ct++) {
            int col = ct * 16 + mrow;
#pragma unroll
            for (int h = 0; h < 2; h++)
#pragma unroll
                for (int r = 0; r < 4; r++) {
                    int node = base + h * 16 + quad * 4 + r;
                    float v = acc[h][ct][r] + bias[ct];
                    H[(size_t)node * 256 + col] = f2bf(fmaxf(v, 0.f));
                }
        }
    }
}

// ---- persistent GEMM2: cols 0..127 -> g (fp8), cols 128..255 -> out f32 (+b2) ----
__global__ __launch_bounds__(256, 1) void k_gemm2(const unsigned short* A, const unsigned short* wb,
                                                  const float* b2, unsigned char* g, float* out) {
    __shared__ unsigned short Bs[256 * 256];   // 128 KB
    int t = threadIdx.x;
    {
        const short8* src = (const short8*)wb;
        short8* dst = (short8*)Bs;
#pragma unroll
        for (int i = 0; i < 32; i++) dst[i * 256 + t] = src[i * 256 + t];
    }
    __syncthreads();
    int wv = t >> 6, lane = t & 63;
    int mrow = lane & 15, quad = lane >> 4;
    float bias[8];
#pragma unroll
    for (int i = 0; i < 8; i++) bias[i] = b2[i * 16 + mrow];
    for (int chunk = blockIdx.x; chunk < NCHUNK; chunk += gridDim.x) {
        int base = chunk * 128 + wv * 32;
        if (base >= NN) continue;
        short8 afr[2][8];
#pragma unroll
        for (int kk = 0; kk < 8; kk++) {
            afr[0][kk] = *(const short8*)(A + (size_t)(base + mrow) * 256 + kk * 32 + quad * 8);
            afr[1][kk] = *(const short8*)(A + (size_t)(base + 16 + mrow) * 256 + kk * 32 + quad * 8);
        }
        float4v acc[2][16];
#pragma unroll
        for (int h = 0; h < 2; h++)
#pragma unroll
            for (int ct = 0; ct < 16; ct++) acc[h][ct] = (float4v)(0.0f);
#pragma unroll
        for (int kk = 0; kk < 8; kk++) {
            int koff = kk * 32 + quad * 8;
#pragma unroll
            for (int ct = 0; ct < 16; ct++) {
                short8 b = *(const short8*)(Bs + (ct * 16 + mrow) * 256 + koff);
                acc[0][ct] = __builtin_amdgcn_mfma_f32_16x16x32_bf16(afr[0][kk], b, acc[0][ct], 0, 0, 0);
                acc[1][ct] = __builtin_amdgcn_mfma_f32_16x16x32_bf16(afr[1][kk], b, acc[1][ct], 0, 0, 0);
            }
        }
#pragma unroll
        for (int ct = 0; ct < 16; ct++) {
            int col = ct * 16 + mrow;
#pragma unroll
            for (int h = 0; h < 2; h++)
#pragma unroll
                for (int r = 0; r < 4; r++) {
                    int node = base + h * 16 + quad * 4 + r;
                    float v = acc[h][ct][r];
                    if (ct < 8) g[(size_t)node * 128 + col] = f2fp8(v);
                    else        out[(size_t)node * 128 + (col - 128)] = v + bias[ct - 8];
                }
        }
    }
}

extern "C" void kernel_launch(void* const* d_in, const int* in_sizes, int n_in,
                              void* d_out, int out_size, void* d_ws, size_t ws_size,
                              hipStream_t stream) {
    const float* x   = (const float*)d_in[0];
    const int*   ei  = (const int*)d_in[1];
    const float* W1l = (const float*)d_in[2];
    const float* b1  = (const float*)d_in[3];
    const float* W1r = (const float*)d_in[4];
    const float* W2l = (const float*)d_in[5];
    const float* b2  = (const float*)d_in[6];
    const float* W2r = (const float*)d_in[7];
    float* out = (float*)d_out;

    char* p = (char*)d_ws;
    unsigned int* axb = (unsigned int*)p; p += (size_t)NN * 256 * 2;  // [agg(128) | x(128)] bf16
    unsigned short* h = (unsigned short*)p; p += (size_t)NN * 256 * 2;
    unsigned char* g  = (unsigned char*)p; p += (size_t)NN * 128;     // fp8 e4m3
    unsigned short* xf8 = (unsigned short*)p; p += (size_t)NN * 128;  // fp8 e4m3 copy of x
    unsigned short* wb1 = (unsigned short*)p; p += 65536 * 2;
    unsigned short* wb2 = (unsigned short*)p; p += 65536 * 2;
    int* deg  = (int*)p; p += (size_t)NN * 4;
    int* off  = (int*)p; p += (size_t)NN * 4;
    int* csr  = (int*)p; p += (size_t)NE * 4;
    int* bcnt = (int*)p; p += NB * 4;
    int* boff = (int*)p; p += (NB + 1) * 4;
    int* bcur = (int*)p; p += NB * 4;
    if (ws_size < (size_t)(p - (char*)d_ws)) return;
    uint2* pairs = (uint2*)h;   // overlay: pairs dead before gemm1 writes h

    hipMemsetAsync(bcnt, 0, NB * 4, stream);
    k_prep<<<25384, 256, 0, stream>>>(x, W1l, W1r, W2l, W2r, ei, axb, xf8, wb1, wb2, bcnt);
    k_bscan<<<1, NB, 0, stream>>>(bcnt, boff, bcur);
    k_bscatter<<<NCH, 256, 0, stream>>>(ei, bcur, pairs);
    k_build<<<NB, 256, 0, stream>>>(pairs, boff, off, deg, csr);
    k_agg1<<<NN * 64 / 256, 256, 0, stream>>>((const uint2*)xf8, off, deg, csr, axb);
    k_gemm1<<<256, 256, 0, stream>>>((const unsigned short*)axb, wb1, b1, h);
    k_gemm2<<<256, 256, 0, stream>>>(h, wb2, b2, g, out);
    k_agg2<<<25000, 256, 0, stream>>>((const uint2*)g, off, deg, csr, out);
}

// Round 7
// 365.451 us; speedup vs baseline: 1.1229x; 1.0057x over previous
//
#include <hip/hip_runtime.h>
#include <hip/hip_bf16.h>
#include <hip/hip_fp16.h>

#define NN 100000
#define NE 1600000
#define NCHUNK ((NN + 127) / 128)   // 782 (gemm row chunks of 128)
#define NPB 512                      // nodes per bucket (pow2, shift 9)
#define NB 256                       // bucket slots (196 active)
#define CHUNK 8192                   // edges per bscatter block
#define NCH ((NE + CHUNK - 1) / CHUNK)  // 196

typedef __attribute__((ext_vector_type(8))) short short8;
typedef __attribute__((ext_vector_type(4))) float float4v;
typedef __attribute__((ext_vector_type(2))) float float2v;

__device__ __forceinline__ unsigned short f2bf(float f) {
    unsigned int b = __float_as_uint(f);
    return (unsigned short)((b + 0x7fffu + ((b >> 16) & 1u)) >> 16);
}
__device__ __forceinline__ unsigned int pack_bf16(float lo, float hi) {
    return (unsigned int)f2bf(lo) | ((unsigned int)f2bf(hi) << 16);
}
// 8 fp8 (e4m3) in a uint2 -> accumulate into a[0..7]
__device__ __forceinline__ void addp8(float* a, uint2 u) {
    float2v f;
    f = __builtin_amdgcn_cvt_pk_f32_fp8(u.x, false); a[0] += f.x; a[1] += f.y;
    f = __builtin_amdgcn_cvt_pk_f32_fp8(u.x, true);  a[2] += f.x; a[3] += f.y;
    f = __builtin_amdgcn_cvt_pk_f32_fp8(u.y, false); a[4] += f.x; a[5] += f.y;
    f = __builtin_amdgcn_cvt_pk_f32_fp8(u.y, true);  a[6] += f.x; a[7] += f.y;
}
__device__ __forceinline__ unsigned char f2fp8(float v) {
    int r = __builtin_amdgcn_cvt_pk_fp8_f32(v, v, 0, false);
    return (unsigned char)(r & 0xff);
}
__device__ __forceinline__ unsigned short pack2fp8(float lo, float hi) {
    int r = __builtin_amdgcn_cvt_pk_fp8_f32(lo, hi, 0, false);
    return (unsigned short)(r & 0xffff);
}
__device__ __forceinline__ float h2f(unsigned short u) {
    return __half2float(__ushort_as_half(u));
}

// ---- fused prep: xconv (blocks 0..24999), wconv (25000..25127), bcount (25128..25383) ----
__global__ void k_prep(const float* x, const float* W1l, const float* W1r,
                       const float* W2l, const float* W2r, const int* ei,
                       unsigned int* axb_u, unsigned short* xf8, unsigned short* wb1,
                       unsigned short* wb2, int* bcnt) {
    __shared__ int hh[NB];
    int b = blockIdx.x, t = threadIdx.x;
    if (b < 25000) {
        int tt = b * 256 + t;
        int node = tt >> 6, i = tt & 63;
        float2 v = ((const float2*)x)[tt];
        axb_u[(size_t)node * 128 + 64 + i] = pack_bf16(v.x, v.y);
        xf8[(size_t)node * 64 + i] = pack2fp8(v.x, v.y);
    } else if (b < 25128) {
        int i = (b - 25000) * 256 + t;        // < 32768
        int r1 = i >> 7, c1 = i & 127;        // W1l/W1r are 256x128
        wb1[r1 * 256 + c1]       = f2bf(W1l[i]);
        wb1[r1 * 256 + 128 + c1] = f2bf(W1r[i]);
        wb2[i]         = f2bf(W2l[i]);        // 128x256, k contiguous
        wb2[32768 + i] = f2bf(W2r[i]);
    } else {
        hh[t] = 0;
        __syncthreads();
        int e0 = (b - 25128) * 6250;          // 256 * 6250 = NE exactly
        for (int e = e0 + t; e < e0 + 6250; e += 256)
            atomicAdd(&hh[ei[NE + e] >> 9], 1);
        __syncthreads();
        if (hh[t]) atomicAdd(&bcnt[t], hh[t]);
    }
}

__global__ void k_bscan(const int* bcnt, int* boff, int* bcur) {
    __shared__ int s[NB];
    int t = threadIdx.x;
    int v = bcnt[t];
    s[t] = v;
    __syncthreads();
    for (int d = 1; d < NB; d <<= 1) {
        int val = (t >= d) ? s[t - d] : 0;
        __syncthreads();
        s[t] += val;
        __syncthreads();
    }
    boff[t + 1] = s[t];
    if (t == 0) boff[0] = 0;
    bcur[t] = s[t] - v;   // exclusive
}

// pairs packed: bits[0:17)=row, bits[17:26)=col&511 (bucket-local)
__global__ __launch_bounds__(256) void k_bscatter(const int* ei, int* bcur, unsigned int* pairs) {
    __shared__ unsigned int buf[CHUNK];   // 32 KB
    __shared__ int cnt[NB];
    __shared__ int lbase[NB];
    __shared__ int lcur[NB];
    __shared__ int gpos[NB];
    int t = threadIdx.x;
    int e0 = blockIdx.x * CHUNK;
    int nedge = NE - e0; if (nedge > CHUNK) nedge = CHUNK;
    cnt[t] = 0;
    __syncthreads();
    for (int i = t; i < nedge; i += 256)
        atomicAdd(&cnt[ei[NE + e0 + i] >> 9], 1);
    __syncthreads();
    int v = cnt[t];
    lcur[t] = v;
    __syncthreads();
    for (int d = 1; d < NB; d <<= 1) {
        int val = (t >= d) ? lcur[t - d] : 0;
        __syncthreads();
        lcur[t] += val;
        __syncthreads();
    }
    lbase[t] = lcur[t] - v;
    gpos[t] = atomicAdd(&bcur[t], v);
    __syncthreads();
    lcur[t] = lbase[t];
    __syncthreads();
    for (int i = t; i < nedge; i += 256) {
        int r = ei[e0 + i], c = ei[NE + e0 + i];
        int b = c >> 9;
        int p = atomicAdd(&lcur[b], 1);
        buf[p] = (unsigned)r | ((unsigned)(c & 511) << 17);
    }
    __syncthreads();
    // coalesced flush: wave wv handles buckets wv, wv+4, ...; lanes stride inside
    int wv = t >> 6, lane = t & 63;
    for (int b = wv; b < NB; b += 4) {
        int n = cnt[b], lb = lbase[b], gp = gpos[b];
        for (int i = lane; i < n; i += 64)
            pairs[gp + i] = buf[lb + i];
    }
}

__global__ __launch_bounds__(256) void k_build(const unsigned int* pairs, const int* boff,
                                               int* off, int* deg, int* csr) {
    __shared__ int ldeg[NPB];
    __shared__ int lcur[NPB];
    __shared__ int sscan[256];
    int b = blockIdx.x;
    int nbase = b * NPB;
    if (nbase >= NN) return;
    int t = threadIdx.x;
    int base = boff[b], cntb = boff[b + 1] - base;
    ldeg[t] = 0; ldeg[t + 256] = 0;
    __syncthreads();
    for (int i = t; i < cntb; i += 256) {
        unsigned int pr = pairs[base + i];
        atomicAdd(&ldeg[pr >> 17], 1);
    }
    __syncthreads();
    int d0 = ldeg[2 * t], d1 = ldeg[2 * t + 1];
    int v = d0 + d1;
    sscan[t] = v;
    __syncthreads();
    for (int d = 1; d < 256; d <<= 1) {
        int val = (t >= d) ? sscan[t - d] : 0;
        __syncthreads();
        sscan[t] += val;
        __syncthreads();
    }
    int ex = sscan[t] - v;
    lcur[2 * t] = ex; lcur[2 * t + 1] = ex + d0;
    __syncthreads();
    int nloc = NN - nbase; if (nloc > NPB) nloc = NPB;
    for (int ln = t; ln < nloc; ln += 256) {
        off[nbase + ln] = base + lcur[ln];
        deg[nbase + ln] = ldeg[ln];
    }
    __syncthreads();
    for (int i = t; i < cntb; i += 256) {
        unsigned int pr = pairs[base + i];
        int p = atomicAdd(&lcur[pr >> 17], 1);
        csr[base + p] = (int)(pr & 0x1FFFFu);
    }
}

// ---- agg1: mean of xf8 (fp8) over neighbors -> axb cols 0..127 (bf16) ----
__global__ void k_agg1(const uint2* xf8, const int* off, const int* deg,
                       const int* csr, unsigned int* axb_w) {
    int wid = (blockIdx.x * 256 + threadIdx.x) >> 6;
    if (wid >= NN) return;
    int lane = threadIdx.x & 63;
    int sub = lane >> 4, l16 = lane & 15;
    int start = off[wid], d = deg[wid];
    const uint2* gp = xf8 + l16;   // row stride = 16 uint2 (128 B)
    float a[8] = {0.f, 0.f, 0.f, 0.f, 0.f, 0.f, 0.f, 0.f};
    int j = sub;
    for (; j + 4 < d; j += 8) {
        int n0 = csr[start + j];
        int n1 = csr[start + j + 4];
        uint2 u0 = gp[(size_t)n0 * 16];
        uint2 u1 = gp[(size_t)n1 * 16];
        addp8(a, u0); addp8(a, u1);
    }
    if (j < d) {
        int nb = csr[start + j];
        uint2 u = gp[(size_t)nb * 16];
        addp8(a, u);
    }
#pragma unroll
    for (int i = 0; i < 8; i++) {
        a[i] += __shfl_xor(a[i], 16, 64);
        a[i] += __shfl_xor(a[i], 32, 64);
    }
    if (sub == 0) {
        float inv = 1.0f / (float)(d > 0 ? d : 1);
        uint4 o;
        o.x = pack_bf16(a[0] * inv, a[1] * inv);
        o.y = pack_bf16(a[2] * inv, a[3] * inv);
        o.z = pack_bf16(a[4] * inv, a[5] * inv);
        o.w = pack_bf16(a[6] * inv, a[7] * inv);
        *(uint4*)(axb_w + (size_t)wid * 128 + (l16 << 2)) = o;
    }
}

// ---- agg2: out = partial(f16) + mean of g (fp8) over neighbors ----
__global__ void k_agg2(const uint2* g, const int* off, const int* deg,
                       const int* csr, const unsigned short* partial, float* out) {
    int wid = (blockIdx.x * 256 + threadIdx.x) >> 6;
    if (wid >= NN) return;
    int lane = threadIdx.x & 63;
    int sub = lane >> 4, l16 = lane & 15;
    int start = off[wid], d = deg[wid];
    const uint2* gp = g + l16;   // row stride = 16 uint2 (128 B)
    float a[8] = {0.f, 0.f, 0.f, 0.f, 0.f, 0.f, 0.f, 0.f};
    int j = sub;
    for (; j + 4 < d; j += 8) {
        int n0 = csr[start + j];
        int n1 = csr[start + j + 4];
        uint2 u0 = gp[(size_t)n0 * 16];
        uint2 u1 = gp[(size_t)n1 * 16];
        addp8(a, u0); addp8(a, u1);
    }
    if (j < d) {
        int nb = csr[start + j];
        uint2 u = gp[(size_t)nb * 16];
        addp8(a, u);
    }
#pragma unroll
    for (int i = 0; i < 8; i++) {
        a[i] += __shfl_xor(a[i], 16, 64);
        a[i] += __shfl_xor(a[i], 32, 64);
    }
    if (sub == 0) {
        float inv = 1.0f / (float)(d > 0 ? d : 1);
        uint4 pu = *(const uint4*)(partial + (size_t)wid * 128 + (l16 << 3));
        float4 c0, c1;
        c0.x = h2f(pu.x & 0xffff) + a[0] * inv; c0.y = h2f(pu.x >> 16) + a[1] * inv;
        c0.z = h2f(pu.y & 0xffff) + a[2] * inv; c0.w = h2f(pu.y >> 16) + a[3] * inv;
        c1.x = h2f(pu.z & 0xffff) + a[4] * inv; c1.y = h2f(pu.z >> 16) + a[5] * inv;
        c1.z = h2f(pu.w & 0xffff) + a[6] * inv; c1.w = h2f(pu.w >> 16) + a[7] * inv;
        float4* po = (float4*)(out + (size_t)wid * 128) + (l16 << 1);
        po[0] = c0; po[1] = c1;
    }
}

// ---- persistent GEMM1: relu(A@wb1^T + b1) -> H (bf16) ----
__global__ __launch_bounds__(256, 1) void k_gemm1(const unsigned short* A, const unsigned short* wb,
                                                  const float* b1, unsigned short* H) {
    __shared__ unsigned short Bs[256 * 256];   // 128 KB
    int t = threadIdx.x;
    {
        const short8* src = (const short8*)wb;
        short8* dst = (short8*)Bs;
#pragma unroll
        for (int i = 0; i < 32; i++) dst[i * 256 + t] = src[i * 256 + t];
    }
    __syncthreads();
    int wv = t >> 6, lane = t & 63;
    int mrow = lane & 15, quad = lane >> 4;
    float bias[16];
#pragma unroll
    for (int ct = 0; ct < 16; ct++) bias[ct] = b1[ct * 16 + mrow];
    for (int chunk = blockIdx.x; chunk < NCHUNK; chunk += gridDim.x) {
        int base = chunk * 128 + wv * 32;
        if (base >= NN) continue;
        short8 afr[2][8];
#pragma unroll
        for (int kk = 0; kk < 8; kk++) {
            afr[0][kk] = *(const short8*)(A + (size_t)(base + mrow) * 256 + kk * 32 + quad * 8);
            afr[1][kk] = *(const short8*)(A + (size_t)(base + 16 + mrow) * 256 + kk * 32 + quad * 8);
        }
        float4v acc[2][16];
#pragma unroll
        for (int h = 0; h < 2; h++)
#pragma unroll
            for (int ct = 0; ct < 16; ct++) acc[h][ct] = (float4v)(0.0f);
#pragma unroll
        for (int kk = 0; kk < 8; kk++) {
            int koff = kk * 32 + quad * 8;
#pragma unroll
            for (int ct = 0; ct < 16; ct++) {
                short8 b = *(const short8*)(Bs + (ct * 16 + mrow) * 256 + koff);
                acc[0][ct] = __builtin_amdgcn_mfma_f32_16x16x32_bf16(afr[0][kk], b, acc[0][ct], 0, 0, 0);
                acc[1][ct] = __builtin_amdgcn_mfma_f32_16x16x32_bf16(afr[1][kk], b, acc[1][ct], 0, 0, 0);
            }
        }
#pragma unroll
        for (int ct = 0; ct < 16; ct++) {
            int col = ct * 16 + mrow;
#pragma unroll
            for (int h = 0; h < 2; h++)
#pragma unroll
                for (int r = 0; r < 4; r++) {
                    int node = base + h * 16 + quad * 4 + r;
                    float v = acc[h][ct][r] + bias[ct];
                    H[(size_t)node * 256 + col] = f2bf(fmaxf(v, 0.f));
                }
        }
    }
}

// ---- persistent GEMM2: cols 0..127 -> g (fp8), cols 128..255 -> partial f16 (+b2) ----
__global__ __launch_bounds__(256, 1) void k_gemm2(const unsigned short* A, const unsigned short* wb,
                                                  const float* b2, unsigned char* g,
                                                  unsigned short* partial) {
    __shared__ unsigned short Bs[256 * 256];   // 128 KB
    int t = threadIdx.x;
    {
        const short8* src = (const short8*)wb;
        short8* dst = (short8*)Bs;
#pragma unroll
        for (int i = 0; i < 32; i++) dst[i * 256 + t] = src[i * 256 + t];
    }
    __syncthreads();
    int wv = t >> 6, lane = t & 63;
    int mrow = lane & 15, quad = lane >> 4;
    float bias[8];
#pragma unroll
    for (int i = 0; i < 8; i++) bias[i] = b2[i * 16 + mrow];
    for (int chunk = blockIdx.x; chunk < NCHUNK; chunk += gridDim.x) {
        int base = chunk * 128 + wv * 32;
        if (base >= NN) continue;
        short8 afr[2][8];
#pragma unroll
        for (int kk = 0; kk < 8; kk++) {
            afr[0][kk] = *(const short8*)(A + (size_t)(base + mrow) * 256 + kk * 32 + quad * 8);
            afr[1][kk] = *(const short8*)(A + (size_t)(base + 16 + mrow) * 256 + kk * 32 + quad * 8);
        }
        float4v acc[2][16];
#pragma unroll
        for (int h = 0; h < 2; h++)
#pragma unroll
            for (int ct = 0; ct < 16; ct++) acc[h][ct] = (float4v)(0.0f);
#pragma unroll
        for (int kk = 0; kk < 8; kk++) {
            int koff = kk * 32 + quad * 8;
#pragma unroll
            for (int ct = 0; ct < 16; ct++) {
                short8 b = *(const short8*)(Bs + (ct * 16 + mrow) * 256 + koff);
                acc[0][ct] = __builtin_amdgcn_mfma_f32_16x16x32_bf16(afr[0][kk], b, acc[0][ct], 0, 0, 0);
                acc[1][ct] = __builtin_amdgcn_mfma_f32_16x16x32_bf16(afr[1][kk], b, acc[1][ct], 0, 0, 0);
            }
        }
#pragma unroll
        for (int ct = 0; ct < 16; ct++) {
            int col = ct * 16 + mrow;
#pragma unroll
            for (int h = 0; h < 2; h++)
#pragma unroll
                for (int r = 0; r < 4; r++) {
                    int node = base + h * 16 + quad * 4 + r;
                    float v = acc[h][ct][r];
                    if (ct < 8) {
                        g[(size_t)node * 128 + col] = f2fp8(v);
                    } else {
                        __half hf = __float2half(v + bias[ct - 8]);
                        partial[(size_t)node * 128 + (col - 128)] = __half_as_ushort(hf);
                    }
                }
        }
    }
}

extern "C" void kernel_launch(void* const* d_in, const int* in_sizes, int n_in,
                              void* d_out, int out_size, void* d_ws, size_t ws_size,
                              hipStream_t stream) {
    const float* x   = (const float*)d_in[0];
    const int*   ei  = (const int*)d_in[1];
    const float* W1l = (const float*)d_in[2];
    const float* b1  = (const float*)d_in[3];
    const float* W1r = (const float*)d_in[4];
    const float* W2l = (const float*)d_in[5];
    const float* b2  = (const float*)d_in[6];
    const float* W2r = (const float*)d_in[7];
    float* out = (float*)d_out;

    char* p = (char*)d_ws;
    unsigned int* axb = (unsigned int*)p; p += (size_t)NN * 256 * 2;  // [agg(128) | x(128)] bf16
    unsigned short* h = (unsigned short*)p; p += (size_t)NN * 256 * 2;
    unsigned char* g  = (unsigned char*)p; p += (size_t)NN * 128;     // fp8 e4m3
    unsigned short* xf8 = (unsigned short*)p; p += (size_t)NN * 128;  // fp8 e4m3 copy of x
    unsigned short* wb1 = (unsigned short*)p; p += 65536 * 2;
    unsigned short* wb2 = (unsigned short*)p; p += 65536 * 2;
    int* deg  = (int*)p; p += (size_t)NN * 4;
    int* off  = (int*)p; p += (size_t)NN * 4;
    int* csr  = (int*)p; p += (size_t)NE * 4;
    int* bcnt = (int*)p; p += NB * 4;
    int* boff = (int*)p; p += (NB + 1) * 4;
    int* bcur = (int*)p; p += NB * 4;
    if (ws_size < (size_t)(p - (char*)d_ws)) return;
    unsigned int* pairs = (unsigned int*)h;       // overlay: dead before gemm1 writes h
    unsigned short* partial = (unsigned short*)axb; // overlay: axb dead after gemm1 reads it

    hipMemsetAsync(bcnt, 0, NB * 4, stream);
    k_prep<<<25384, 256, 0, stream>>>(x, W1l, W1r, W2l, W2r, ei, axb, xf8, wb1, wb2, bcnt);
    k_bscan<<<1, NB, 0, stream>>>(bcnt, boff, bcur);
    k_bscatter<<<NCH, 256, 0, stream>>>(ei, bcur, pairs);
    k_build<<<NB, 256, 0, stream>>>(pairs, boff, off, deg, csr);
    k_agg1<<<NN * 64 / 256, 256, 0, stream>>>((const uint2*)xf8, off, deg, csr, axb);
    k_gemm1<<<256, 256, 0, stream>>>((const unsigned short*)axb, wb1, b1, h);
    k_gemm2<<<256, 256, 0, stream>>>(h, wb2, b2, g, partial);
    k_agg2<<<25000, 256, 0, stream>>>((const uint2*)g, off, deg, csr, partial, out);
}